// Round 9
// baseline (188.091 us; speedup 1.0000x reference)
//
#include <hip/hip_runtime.h>
#include <hip/hip_bf16.h>

// GCN layer: out = relu( D^-1/2 (dedup(A) + I) D^-1/2 (X @ W) )
// N=10000, E=320000, F=256.
// Storage: fp32 X/W/out (PROVEN r9/r10). Edges: int32 expected, int64
// tolerated via per-wave ballot detect.
// Cost model (r1-r8 measured):
//  - ANY pass doing ~320k device-scope atomic RMWs over a multi-MB region
//    costs 45-50us: chained (r1 51), fire-forget (r3 49), NT-zeroed lines
//    (r7 50), XCD-partitioned (r8 fillp ~45 by subtraction). Locality and
//    chain structure are irrelevant -> global bitmap abandoned.
//  - r8 REVEAL: the old GEMM path was ~50us itself (bucket+gemm=53 with a
//    trivially-cheap bucket path; MfmaUtil 0.85%, VGPR 64): one wave/SIMD,
//    acc[16]=64 VGPR starved the scheduler -> serialized L2-latency chain.
//  - Dense small-target atomics (deg, 40KB) are tolerable; LDS-hist
//    replacement regressed (r7).
// THIS ROUND:
//  (1) GEMM-v2: 625 blocks x 4 waves; X strip staged in LDS (bf16,
//      [16][264] pad); each wave 4 col-tiles (acc[4]=16 VGPR). 2500 waves,
//      lean regalloc -> latency hidden. Predict ~50 -> ~10us.
//  (2) k_fillscan: dedup WITHOUT a global bitmap. Bucketed region entries
//      pack (s,t) in one word; 400 blocks x 25 rows stream their partition
//      slice blindly (sentinel -1), ds_or into a 32KB LDS bitmap (no
//      dependent lazy loads -- r4's mistake avoided), then the proven
//      popcount+prefix scan runs FROM LDS -> adj/cnt + dense deg atomics.
// 4 launches: k_pre -> k_bucket_gemm -> k_fillscan -> k_gather.
// r8: no cooperative mega-kernel. r6: GEMM merge only at BLOCK level.
//
// ws layout (bytes), ~13.1 MB (ws is 256 MiB):
//   deg    i32[N]         @ 0
//   cnt    i32[N]         @ 40,960
//   adj    i32[N*96]      @ 81,920
//   Wt     bf16[F*F]      @ 3,921,920
//   H      bf16[N*F]      @ 4,052,992
//   cntpb  i32[8*1250]    @ 9,172,992
//   region i32[8*1250*96] @ 9,212,992  (3.84 MB packed bucketed edges)

constexpr int N = 10000;
constexpr int E = 320000;
constexpr int F = 256;
constexpr int DEGCAP = 96;   // Poisson(32): P(any deduped degree >= 96) ~ 1e-16
constexpr int NPART = 8;
constexpr int PROWS = 1250;  // rows per partition
constexpr int RCAP = 96;     // per-(block,partition) bucket cap (+12 sigma)
constexpr int FROWS = 25;    // rows per fillscan block (50 blocks/partition)

constexpr size_t OFF_DEG   = 0;
constexpr size_t OFF_CNT   = 40960;
constexpr size_t OFF_ADJ   = 81920;
constexpr size_t OFF_WT    = OFF_ADJ + 4ull * N * DEGCAP;      // 3,921,920
constexpr size_t OFF_H     = OFF_WT + 2ull * F * F;            // 4,052,992
constexpr size_t OFF_CNTPB = OFF_H + 2ull * N * F;             // 9,172,992
constexpr size_t OFF_REG   = OFF_CNTPB + 4ull * NPART * PROWS; // 9,212,992

constexpr int BKT_BLKS  = (E + 255) / 256;   // 1250
constexpr int GEMM_BLKS = N / 16;            // 625 (one 16-row strip per block)
constexpr int FS_BLKS   = N / FROWS;         // 400
constexpr int REG_INTS  = NPART * PROWS * RCAP;  // 960,000
constexpr int SLICE_U4  = PROWS * RCAP / 4;      // 30,000 uint4 per partition slice

typedef short s8v __attribute__((ext_vector_type(8)));   // 8 bf16 = 4 VGPRs
typedef float f4v __attribute__((ext_vector_type(4)));   // MFMA accumulator
typedef unsigned u4v __attribute__((ext_vector_type(4)));  // native vec for NT store

__device__ __forceinline__ float bf2f(unsigned short u) {
    union { unsigned u; float f; } c; c.u = (unsigned)u << 16; return c.f;
}
__device__ __forceinline__ unsigned short f2bf(float f) {
    union { __hip_bfloat16 b; unsigned short s; } c; c.b = __float2bfloat16(f); return c.s;
}

// 256 blocks: deg=1; cntpb=0; region=-1 sentinel (NT, 960k ints = 4 iters);
// blocks 0-63: W (fp32) -> Wt (bf16, transposed). cnt needs no init.
__global__ void k_pre(int* __restrict__ deg, int* __restrict__ cntpb,
                      const float* __restrict__ W, unsigned short* __restrict__ Wt,
                      u4v* __restrict__ region4) {
    __shared__ unsigned short ls[4][F];
    int i = blockIdx.x * blockDim.x + threadIdx.x;
    if (i < N) { deg[i] = 1; cntpb[i] = 0; }  // NPART*PROWS == N

    u4v z = {0xFFFFFFFFu, 0xFFFFFFFFu, 0xFFFFFFFFu, 0xFFFFFFFFu};
    for (int b = i; b < REG_INTS / 4; b += 256 * 256)
        __builtin_nontemporal_store(z, &region4[b]);

    if (blockIdx.x < 64) {
        int n0 = blockIdx.x * 4;
        int k = threadIdx.x;
        float4 v = *(const float4*)&W[k * F + n0];
        ls[0][k] = f2bf(v.x); ls[1][k] = f2bf(v.y);
        ls[2][k] = f2bf(v.z); ls[3][k] = f2bf(v.w);
        __syncthreads();
        int nn = threadIdx.x >> 6;
        int kk = (threadIdx.x & 63) * 4;
        uint2 o;
        o.x = (unsigned)ls[nn][kk]     | ((unsigned)ls[nn][kk + 1] << 16);
        o.y = (unsigned)ls[nn][kk + 2] | ((unsigned)ls[nn][kk + 3] << 16);
        *(uint2*)&Wt[(n0 + nn) * F + kk] = o;
    }
}

// Fused bucket + GEMM-v2, block-level split.
// Blocks [0, BKT_BLKS): route 256 edges into 8 partition buckets in LDS,
//   flush to region[p][block][.] with plain stores. Packed entry:
//   (s - p*1250) << 14 | t  (< 2^25, never negative; -1 = empty sentinel).
// Blocks [BKT_BLKS, +GEMM_BLKS): H = bf16(X) @ bf16(W), MFMA 16x16x32.
//   One block per 16-row strip, 4 waves: stage X strip -> LDS bf16
//   [16][264] (pad breaks the 16-way ds_read bank conflict to free 2-way),
//   wave w computes col-tiles 4w..4w+3 (acc[4] = 16 VGPR -- r8 showed
//   acc[16]=64 VGPR starved regalloc to a serial load chain, MfmaUtil 0.9%).
//   C layout: col=lane&15, row=(lane>>4)*4+reg [learn_hip m89/m91].
__global__ void __launch_bounds__(256) k_bucket_gemm(
    const int* __restrict__ edges, int* __restrict__ cntpb,
    int* __restrict__ region,
    const float* __restrict__ X, const unsigned short* __restrict__ Wt,
    unsigned short* __restrict__ H) {
    __shared__ int bkt[NPART][RCAP];
    __shared__ int bcnt[NPART];
    __shared__ unsigned short lsA[16][264];  // 16 rows x 256 bf16 (+8 pad)
    int tid = threadIdx.x;

    if (blockIdx.x < BKT_BLKS) {
        int probe = edges[2 * (tid & 63) + 1];
        bool is32 = __ballot(probe != 0) != 0ull;
        if (tid < NPART) bcnt[tid] = 0;
        __syncthreads();
        int e = blockIdx.x * 256 + tid;
        if (e < E) {
            int s, t;
            if (is32) { s = edges[e];     t = edges[E + e]; }
            else      { s = edges[2 * e]; t = edges[2 * E + 2 * e]; }
            if ((unsigned)s < (unsigned)N && (unsigned)t < (unsigned)N) {
                int p = s / PROWS;
                int v = ((s - p * PROWS) << 14) | t;
                int pos = atomicAdd(&bcnt[p], 1);  // LDS atomic: cheap
                if (pos < RCAP) bkt[p][pos] = v;
            }
        }
        __syncthreads();
        int wv = tid >> 6, ln = tid & 63;
#pragma unroll
        for (int q = 0; q < 2; ++q) {
            int p = wv * 2 + q;
            int c = bcnt[p]; if (c > RCAP) c = RCAP;
            int* dst = region + ((size_t)p * BKT_BLKS + blockIdx.x) * RCAP;
            for (int i2 = ln; i2 < c; i2 += 64) dst[i2] = bkt[p][i2];
            if (ln == 0) cntpb[p * BKT_BLKS + blockIdx.x] = c;
        }
        return;
    }
    // --- GEMM-v2 path ---
    int r0 = (blockIdx.x - BKT_BLKS) * 16;
    {   // stage: thread tid -> row tid>>4, 16 cols starting (tid&15)*16
        int row = tid >> 4, seg = tid & 15;
        const float4* src = (const float4*)(X + (r0 + row) * F + seg * 16);
#pragma unroll
        for (int j = 0; j < 4; ++j) {
            float4 v = src[j];
            uint2 o;
            o.x = (unsigned)f2bf(v.x) | ((unsigned)f2bf(v.y) << 16);
            o.y = (unsigned)f2bf(v.z) | ((unsigned)f2bf(v.w) << 16);
            *(uint2*)&lsA[row][seg * 16 + j * 4] = o;
        }
    }
    __syncthreads();
    int lane = tid & 63, wv = tid >> 6;
    int m = lane & 15, q = lane >> 4;
    const s8v* B = (const s8v*)(Wt + m * F + q * 8);  // + t*512 per col-tile
    f4v acc[4] = {};
#pragma unroll
    for (int kk = 0; kk < 8; ++kk) {
        s8v af = *(const s8v*)&lsA[m][kk * 32 + q * 8];
#pragma unroll
        for (int tt = 0; tt < 4; ++tt) {
            int t = wv * 4 + tt;
            s8v bf = B[t * 512 + kk * 4];
            acc[tt] = __builtin_amdgcn_mfma_f32_16x16x32_bf16(af, bf, acc[tt], 0, 0, 0);
        }
    }
#pragma unroll
    for (int tt = 0; tt < 4; ++tt) {
        int col = (wv * 4 + tt) * 16 + m;
#pragma unroll
        for (int i = 0; i < 4; ++i)
            H[(r0 + q * 4 + i) * F + col] = f2bf(acc[tt][i]);
    }
}

// Atomic-free dedup: 400 blocks x 25 rows. Block b owns global rows
// [b*25, b*25+25) within partition p = b/50. Stream the ENTIRE partition
// slice (1250*96 ints incl. -1 sentinels -- blind uint4 reads, no dependent
// loads), ds_or hits into a 25x320-word LDS bitmap (32 KB). Then the proven
// popcount + wave-prefix scan runs from LDS: adj/cnt exact, deg[t]++
// fire-and-forget (dense 40KB target, measured-tolerable).
__global__ void __launch_bounds__(256) k_fillscan(
    const int* __restrict__ cntpb, const int* __restrict__ region,
    int* __restrict__ adj, int* __restrict__ cnt, int* __restrict__ deg) {
    __shared__ unsigned bmp[FROWS][320];  // 32,000 B
    int tid = threadIdx.x;
    {   // zero LDS bitmap
        u4v z = {0u, 0u, 0u, 0u};
        u4v* z4 = (u4v*)&bmp[0][0];
        for (int i = tid; i < FROWS * 320 / 4; i += 256) z4[i] = z;
    }
    __syncthreads();

    int p = blockIdx.x / (PROWS / FROWS);          // partition 0..7
    int rbase = (blockIdx.x % (PROWS / FROWS)) * FROWS;  // row base within partition
    const u4v* slice = (const u4v*)(region + (size_t)p * PROWS * RCAP);
    for (int i = tid; i < SLICE_U4; i += 256) {
        u4v v4 = slice[i];
#pragma unroll
        for (int j = 0; j < 4; ++j) {
            int v = (int)v4[j];
            if (v >= 0) {
                int r = (v >> 14) - rbase;
                if ((unsigned)r < (unsigned)FROWS) {
                    unsigned t = (unsigned)(v & 16383);
                    atomicOr(&bmp[r][t >> 5], 1u << (t & 31));  // LDS ds_or
                }
            }
        }
    }
    __syncthreads();

    int wave = tid >> 6, lane = tid & 63;
    for (int r = wave; r < FROWS; r += 4) {
        int s = blockIdx.x * FROWS + r;
        const unsigned* row = bmp[r];
        unsigned w0 = row[lane];
        unsigned w1 = row[lane + 64];
        unsigned w2 = row[lane + 128];
        unsigned w3 = row[lane + 192];
        unsigned w4 = row[lane + 256];
        int pc = __popc(w0) + __popc(w1) + __popc(w2) + __popc(w3) + __popc(w4);
        int sc = pc;
#pragma unroll
        for (int d = 1; d < 64; d <<= 1) {
            int v = __shfl_up(sc, d);
            if (lane >= d) sc += v;
        }
        int o = sc - pc;
        if (lane == 63) cnt[s] = sc < DEGCAP ? sc : DEGCAP;
        int* arow = adj + s * DEGCAP;
        unsigned wvs[5] = {w0, w1, w2, w3, w4};
#pragma unroll
        for (int j = 0; j < 5; ++j) {
            unsigned w = wvs[j];
            int base = (j * 64 + lane) * 32;
            while (w) {
                int b = __ffs(w) - 1;
                w &= w - 1;
                int t = base + b;
                if (o < DEGCAP) arow[o] = t;
                ++o;
                atomicAdd(&deg[t], 1);  // dense 40KB target
            }
        }
    }
}

#define ACC8(hv, dv)                                          \
    p0 += dv * bf2f((unsigned short)(hv.x & 0xFFFF));         \
    p1 += dv * bf2f((unsigned short)(hv.x >> 16));            \
    p2 += dv * bf2f((unsigned short)(hv.y & 0xFFFF));         \
    p3 += dv * bf2f((unsigned short)(hv.y >> 16));            \
    p4 += dv * bf2f((unsigned short)(hv.z & 0xFFFF));         \
    p5 += dv * bf2f((unsigned short)(hv.z >> 16));            \
    p6 += dv * bf2f((unsigned short)(hv.w & 0xFFFF));         \
    p7 += dv * bf2f((unsigned short)(hv.w >> 16));

// r7/r10-proven gather, fp32 output (UNCHANGED -- next round's target).
__global__ void k_gather(const int* __restrict__ adj, const int* __restrict__ cnt,
                         const int* __restrict__ deg,
                         const unsigned short* __restrict__ H,
                         float* __restrict__ out) {
    int wave = threadIdx.x >> 6;
    int lane = threadIdx.x & 63;
    int s = blockIdx.x * 4 + wave;  // N = 2500*4 exactly
    int half = lane >> 5, hl = lane & 31;
    const uint4* H16 = (const uint4*)H;
    float ds = rsqrtf((float)deg[s]);
    int c = cnt[s]; if (c > DEGCAP) c = DEGCAP;
    const int* a = adj + s * DEGCAP;
    int tl = 0; float dl = 0.0f;
    if (lane < c) { tl = a[lane]; dl = rsqrtf((float)deg[tl]); }

    uint4 hs = H16[s * 32 + hl];
    float p0, p1, p2, p3, p4, p5, p6, p7;
    {
        float w = half ? 0.0f : ds;
        p0 = w * bf2f((unsigned short)(hs.x & 0xFFFF));
        p1 = w * bf2f((unsigned short)(hs.x >> 16));
        p2 = w * bf2f((unsigned short)(hs.y & 0xFFFF));
        p3 = w * bf2f((unsigned short)(hs.y >> 16));
        p4 = w * bf2f((unsigned short)(hs.z & 0xFFFF));
        p5 = w * bf2f((unsigned short)(hs.z >> 16));
        p6 = w * bf2f((unsigned short)(hs.w & 0xFFFF));
        p7 = w * bf2f((unsigned short)(hs.w >> 16));
    }
    int cc = c < 64 ? c : 64;
    for (int i = 0; i < cc; i += 8) {
        int i0 = i + half, i1 = i + 2 + half, i2 = i + 4 + half, i3 = i + 6 + half;
        int t0 = __shfl(tl, i0), t1 = __shfl(tl, i1);
        int t2 = __shfl(tl, i2), t3 = __shfl(tl, i3);
        float d0 = __shfl(dl, i0), d1 = __shfl(dl, i1);
        float d2 = __shfl(dl, i2), d3 = __shfl(dl, i3);
        uint4 h0 = H16[t0 * 32 + hl];
        uint4 h1 = H16[t1 * 32 + hl];
        uint4 h2 = H16[t2 * 32 + hl];
        uint4 h3 = H16[t3 * 32 + hl];
        ACC8(h0, d0) ACC8(h1, d1) ACC8(h2, d2) ACC8(h3, d3)
    }
    for (int i = 64; i < c; ++i) {
        int t = a[i];
        float d = half ? 0.0f : rsqrtf((float)deg[t]);
        uint4 h = H16[t * 32 + hl];
        ACC8(h, d)
    }
    p0 += __shfl(p0, lane ^ 32); p1 += __shfl(p1, lane ^ 32);
    p2 += __shfl(p2, lane ^ 32); p3 += __shfl(p3, lane ^ 32);
    p4 += __shfl(p4, lane ^ 32); p5 += __shfl(p5, lane ^ 32);
    p6 += __shfl(p6, lane ^ 32); p7 += __shfl(p7, lane ^ 32);
    p0 = fmaxf(p0 * ds, 0.0f); p1 = fmaxf(p1 * ds, 0.0f);
    p2 = fmaxf(p2 * ds, 0.0f); p3 = fmaxf(p3 * ds, 0.0f);
    p4 = fmaxf(p4 * ds, 0.0f); p5 = fmaxf(p5 * ds, 0.0f);
    p6 = fmaxf(p6 * ds, 0.0f); p7 = fmaxf(p7 * ds, 0.0f);
    float4 o;
    if (half) { o.x = p4; o.y = p5; o.z = p6; o.w = p7; }
    else      { o.x = p0; o.y = p1; o.z = p2; o.w = p3; }
    ((float4*)out)[s * 64 + hl * 2 + half] = o;
}

extern "C" void kernel_launch(void* const* d_in, const int* in_sizes, int n_in,
                              void* d_out, int out_size, void* d_ws, size_t ws_size,
                              hipStream_t stream) {
    const float* X = (const float*)d_in[0];
    const float* W = (const float*)d_in[1];
    const int* edges = (const int*)d_in[2];

    char* ws = (char*)d_ws;
    int* deg           = (int*)(ws + OFF_DEG);
    int* cnt           = (int*)(ws + OFF_CNT);
    int* adj           = (int*)(ws + OFF_ADJ);
    unsigned short* Wt = (unsigned short*)(ws + OFF_WT);
    unsigned short* H  = (unsigned short*)(ws + OFF_H);
    int* cntpb         = (int*)(ws + OFF_CNTPB);
    int* region        = (int*)(ws + OFF_REG);

    k_pre<<<256, 256, 0, stream>>>(deg, cntpb, W, Wt, (u4v*)region);
    k_bucket_gemm<<<BKT_BLKS + GEMM_BLKS, 256, 0, stream>>>(edges, cntpb, region, X, Wt, H);
    k_fillscan<<<FS_BLKS, 256, 0, stream>>>(cntpb, region, adj, cnt, deg);
    k_gather<<<N / 4, 256, 0, stream>>>(adj, cnt, deg, H, (float*)d_out);
}

// Round 11
// 137.101 us; speedup vs baseline: 1.3719x; 1.3719x over previous
//
#include <hip/hip_runtime.h>
#include <hip/hip_bf16.h>

// GCN layer: out = relu( D^-1/2 (dedup(A) + I) D^-1/2 (X @ W) )
// N=10000, E=320000, F=256.
// Storage: fp32 X/W/out (PROVEN r9/r10). Edges: int32 expected, int64
// tolerated via per-wave ballot detect.
// Cost model (r1-r9 measured):
//  - ANY pass doing ~300k+ device-scope atomic RMWs costs 45-50us --
//    INCLUDING the 40KB dense deg target (r2/r8/r9 algebra). Chain
//    structure, line state, locality, target size: all irrelevant.
//  - Redundant multi-block streaming of shared slices is latency-bound at
//    low occupancy (r9 fillscan: 50x redundancy = 88us).
//  - Old GEMM (acc[16], 1 wave/strip) was ~50us: VGPR-starved serial L2
//    chain (r8 reveal, MfmaUtil 0.9%). GEMM-v2: LDS-staged X, acc[4].
//  - LDS atomics (ds_add/ds_or) are cheap; block-level kernel fusion is
//    safe (r3), thread-level is not (r6); no cooperative kernels (r8).
// THIS ROUND (r10 = infra flake "container failed twice"; source audited
// for OOB/LDS/sync hazards, none found -- identical resubmit):
// zero global atomics ANYWHERE + zero redundant reads.
//  k_bucket: 400 row-group LDS buckets (cap 12, init -1), flush RAW
//    19.2KB contiguous blob per block -> region[1250][4800] (24MB, written
//    coalesced once, no prefill, no counts).
//  k_fillscan: block g reads region[j][g*12..+12] for all j (every region
//    byte read EXACTLY once), ds_or into 25x320-word LDS bitmap, popcount+
//    prefix scan -> adj/cnt; deg via byte-lane LDS counters (max 25/byte)
//    flushed to part32[400][2500] (4MB).
//  k_deg: deg[t] = 1 + sum of 400 u8 partials (coalesced, 4MB).
// 5 launches: k_pre(Wt) -> k_bucket_gemm -> k_fillscan -> k_deg -> k_gather.
//
// ws layout (bytes), ~37.2 MB (ws is 256 MiB):
//   deg    i32[N]          @ 0
//   cnt    i32[N]          @ 40,960
//   adj    i32[N*96]       @ 81,920
//   Wt     bf16[F*F]       @ 3,921,920
//   H      bf16[N*F]       @ 4,052,992
//   region i32[1250*4800]  @ 9,172,992   (24 MB raw bucket blobs)
//   part32 u32[400*2500]   @ 33,172,992  (4 MB byte-lane deg partials)

constexpr int N = 10000;
constexpr int E = 320000;
constexpr int F = 256;
constexpr int DEGCAP = 96;   // Poisson(32): P(any deduped degree >= 96) ~ 1e-16
constexpr int GROWS = 25;    // rows per group (fillscan block)
constexpr int NG = N / GROWS;          // 400 groups
constexpr int BCAP = 12;     // per-(src-block,group) cap: Poisson(0.64),
                             // P(>12) ~ 1e-13 x 500k pairs ~ 5e-8
constexpr int REG_PB = NG * BCAP;      // 4800 ints per source block

constexpr size_t OFF_DEG  = 0;
constexpr size_t OFF_CNT  = 40960;
constexpr size_t OFF_ADJ  = 81920;
constexpr size_t OFF_WT   = OFF_ADJ + 4ull * N * DEGCAP;   // 3,921,920
constexpr size_t OFF_H    = OFF_WT + 2ull * F * F;         // 4,052,992
constexpr size_t OFF_REG  = OFF_H + 2ull * N * F;          // 9,172,992
constexpr size_t OFF_PART = OFF_REG + 4ull * 1250 * REG_PB; // 33,172,992

constexpr int BKT_BLKS  = E / 256;   // 1250 (exact)
constexpr int GEMM_BLKS = N / 16;    // 625

typedef short s8v __attribute__((ext_vector_type(8)));   // 8 bf16 = 4 VGPRs
typedef float f4v __attribute__((ext_vector_type(4)));   // MFMA accumulator
typedef unsigned u4v __attribute__((ext_vector_type(4)));

__device__ __forceinline__ float bf2f(unsigned short u) {
    union { unsigned u; float f; } c; c.u = (unsigned)u << 16; return c.f;
}
__device__ __forceinline__ unsigned short f2bf(float f) {
    union { __hip_bfloat16 b; unsigned short s; } c; c.b = __float2bfloat16(f); return c.s;
}

// 64 blocks: W (fp32) -> Wt (bf16, transposed). Nothing else: region needs
// no prefill (raw blob flush writes every byte), cnt/deg/part written
// unconditionally downstream.
__global__ void k_pre(const float* __restrict__ W, unsigned short* __restrict__ Wt) {
    __shared__ unsigned short ls[4][F];
    int n0 = blockIdx.x * 4;
    int k = threadIdx.x;
    float4 v = *(const float4*)&W[k * F + n0];
    ls[0][k] = f2bf(v.x); ls[1][k] = f2bf(v.y);
    ls[2][k] = f2bf(v.z); ls[3][k] = f2bf(v.w);
    __syncthreads();
    int nn = threadIdx.x >> 6;
    int kk = (threadIdx.x & 63) * 4;
    uint2 o;
    o.x = (unsigned)ls[nn][kk]     | ((unsigned)ls[nn][kk + 1] << 16);
    o.y = (unsigned)ls[nn][kk + 2] | ((unsigned)ls[nn][kk + 3] << 16);
    *(uint2*)&Wt[(n0 + nn) * F + kk] = o;
}

// Fused bucket + GEMM-v2, block-level split.
// Blocks [0, BKT_BLKS): 256 edges -> 400 row-group LDS buckets (init -1),
//   then flush the RAW bkt[400][12] blob (19.2KB) contiguous to
//   region[block]. Packed entry: (s % 25) << 14 | t; -1 = empty.
//   Zero global atomics; writes perfectly coalesced.
// Blocks [BKT_BLKS, +GEMM_BLKS): H = bf16(X) @ bf16(W), MFMA 16x16x32.
//   One block per 16-row strip, 4 waves; X strip staged in LDS [16][264]
//   (pad kills bank conflicts); wave w does col-tiles 4w..4w+3 (acc[4]=16
//   VGPR; r8: acc[16]=64 VGPR was a serial L2 chain at MfmaUtil 0.9%).
//   C layout: col=lane&15, row=(lane>>4)*4+reg [learn_hip m89/m91].
__global__ void __launch_bounds__(256) k_bucket_gemm(
    const int* __restrict__ edges, int* __restrict__ region,
    const float* __restrict__ X, const unsigned short* __restrict__ Wt,
    unsigned short* __restrict__ H) {
    __shared__ int bkt[NG][BCAP];   // 19,200 B
    __shared__ int bcnt[NG];        //  1,600 B
    __shared__ unsigned short lsA[16][264];  // 8,448 B (GEMM branch)
    int tid = threadIdx.x;

    if (blockIdx.x < BKT_BLKS) {
        int probe = edges[2 * (tid & 63) + 1];
        bool is32 = __ballot(probe != 0) != 0ull;  // wave-uniform dtype detect
        for (int i = tid; i < NG; i += 256) bcnt[i] = 0;
        int4 mone; mone.x = -1; mone.y = -1; mone.z = -1; mone.w = -1;
        int4* b4 = (int4*)&bkt[0][0];
        for (int i = tid; i < REG_PB / 4; i += 256) b4[i] = mone;
        __syncthreads();
        int e = blockIdx.x * 256 + tid;  // E = 1250*256 exactly
        int s, t;
        if (is32) { s = edges[e];     t = edges[E + e]; }
        else      { s = edges[2 * e]; t = edges[2 * E + 2 * e]; }
        if ((unsigned)s < (unsigned)N && (unsigned)t < (unsigned)N) {
            int g = s / GROWS;
            int v = ((s - g * GROWS) << 14) | t;
            int pos = atomicAdd(&bcnt[g], 1);  // LDS atomic: cheap
            if (pos < BCAP) bkt[g][pos] = v;
        }
        __syncthreads();
        int4* dst = (int4*)(region + (size_t)blockIdx.x * REG_PB);
        for (int i = tid; i < REG_PB / 4; i += 256) dst[i] = b4[i];
        return;
    }
    // --- GEMM-v2 path ---
    int r0 = (blockIdx.x - BKT_BLKS) * 16;
    {   // stage X strip -> LDS bf16
        int row = tid >> 4, seg = tid & 15;
        const float4* src = (const float4*)(X + (r0 + row) * F + seg * 16);
#pragma unroll
        for (int j = 0; j < 4; ++j) {
            float4 v = src[j];
            uint2 o;
            o.x = (unsigned)f2bf(v.x) | ((unsigned)f2bf(v.y) << 16);
            o.y = (unsigned)f2bf(v.z) | ((unsigned)f2bf(v.w) << 16);
            *(uint2*)&lsA[row][seg * 16 + j * 4] = o;
        }
    }
    __syncthreads();
    int lane = tid & 63, wv = tid >> 6;
    int m = lane & 15, q = lane >> 4;
    const s8v* B = (const s8v*)(Wt + m * F + q * 8);
    f4v acc[4] = {};
#pragma unroll
    for (int kk = 0; kk < 8; ++kk) {
        s8v af = *(const s8v*)&lsA[m][kk * 32 + q * 8];
#pragma unroll
        for (int tt = 0; tt < 4; ++tt) {
            int t = wv * 4 + tt;
            s8v bf = B[t * 512 + kk * 4];
            acc[tt] = __builtin_amdgcn_mfma_f32_16x16x32_bf16(af, bf, acc[tt], 0, 0, 0);
        }
    }
#pragma unroll
    for (int tt = 0; tt < 4; ++tt) {
        int col = (wv * 4 + tt) * 16 + m;
#pragma unroll
        for (int i = 0; i < 4; ++i)
            H[(r0 + q * 4 + i) * F + col] = f2bf(acc[tt][i]);
    }
}

// Dedup + scan, zero global atomics, zero redundant reads.
// Block g: read region[j][g*12 .. g*12+12) for all j = 0..1249 (3 uint4
// per j, strided; EVERY region byte read exactly once across the grid),
// ds_or valid entries into 25x320-word LDS bitmap. Then popcount + wave
// prefix -> adj/cnt. deg contributions: byte-lane LDS counters
// (hist32[t>>2] += 1 << 8*(t&3); per-block count <= 25 < 256), flushed
// 10KB coalesced -> part32[g].
__global__ void __launch_bounds__(512) k_fillscan(
    const int* __restrict__ region,
    int* __restrict__ adj, int* __restrict__ cnt, unsigned* __restrict__ part32) {
    __shared__ unsigned bmp[GROWS][320];  // 32,000 B
    __shared__ unsigned hist32[N / 4];    // 10,000 B
    int tid = threadIdx.x;
    {
        u4v z = {0u, 0u, 0u, 0u};
        u4v* z4 = (u4v*)&bmp[0][0];
        for (int i = tid; i < GROWS * 320 / 4; i += 512) z4[i] = z;
        u4v* h4 = (u4v*)hist32;
        for (int i = tid; i < N / 16; i += 512) h4[i] = z;
    }
    __syncthreads();

    int g = blockIdx.x;
    const u4v* reg4 = (const u4v*)region;
    for (int idx = tid; idx < BKT_BLKS * 3; idx += 512) {
        int j = idx / 3, q = idx - 3 * j;
        u4v v4 = reg4[(size_t)j * (REG_PB / 4) + g * 3 + q];
#pragma unroll
        for (int jj = 0; jj < 4; ++jj) {
            int v = (int)v4[jj];
            if (v >= 0) {
                int r = v >> 14;              // 0..24
                unsigned t = (unsigned)(v & 16383);
                atomicOr(&bmp[r][t >> 5], 1u << (t & 31));  // LDS ds_or
            }
        }
    }
    __syncthreads();

    int wave = tid >> 6, lane = tid & 63;
    for (int r = wave; r < GROWS; r += 8) {
        int s = g * GROWS + r;
        const unsigned* row = bmp[r];
        unsigned w0 = row[lane];
        unsigned w1 = row[lane + 64];
        unsigned w2 = row[lane + 128];
        unsigned w3 = row[lane + 192];
        unsigned w4 = row[lane + 256];
        int pc = __popc(w0) + __popc(w1) + __popc(w2) + __popc(w3) + __popc(w4);
        int sc = pc;
#pragma unroll
        for (int d = 1; d < 64; d <<= 1) {
            int v = __shfl_up(sc, d);
            if (lane >= d) sc += v;
        }
        int o = sc - pc;
        if (lane == 63) cnt[s] = sc < DEGCAP ? sc : DEGCAP;
        int* arow = adj + s * DEGCAP;
        unsigned wvs[5] = {w0, w1, w2, w3, w4};
#pragma unroll
        for (int j = 0; j < 5; ++j) {
            unsigned w = wvs[j];
            int base = (j * 64 + lane) * 32;
            while (w) {
                int b = __ffs(w) - 1;
                w &= w - 1;
                int t = base + b;
                if (o < DEGCAP) arow[o] = t;
                ++o;
                atomicAdd(&hist32[t >> 2], 1u << ((t & 3) * 8));  // LDS byte-lane
            }
        }
    }
    __syncthreads();
    {   // coalesced 10KB partial flush
        u4v* src = (u4v*)hist32;
        u4v* dst = (u4v*)(part32 + (size_t)g * (N / 4));
        for (int i = tid; i < N / 16; i += 512) dst[i] = src[i];
    }
}

// deg[t] = 1 (self-loop) + sum of 400 byte-lane partials. Coalesced
// (threads j2, j2+1 read adjacent u32 per b). 4 MB, zero atomics.
__global__ void k_deg(const unsigned* __restrict__ part32, int* __restrict__ deg) {
    int j2 = blockIdx.x * blockDim.x + threadIdx.x;  // 0..2499
    if (j2 >= N / 4) return;
    int s0 = 1, s1 = 1, s2 = 1, s3 = 1;
#pragma unroll 8
    for (int b = 0; b < NG; ++b) {
        unsigned w = part32[(size_t)b * (N / 4) + j2];
        s0 += w & 255; s1 += (w >> 8) & 255; s2 += (w >> 16) & 255; s3 += w >> 24;
    }
    int4 o; o.x = s0; o.y = s1; o.z = s2; o.w = s3;
    *(int4*)&deg[j2 * 4] = o;
}

#define ACC8(hv, dv)                                          \
    p0 += dv * bf2f((unsigned short)(hv.x & 0xFFFF));         \
    p1 += dv * bf2f((unsigned short)(hv.x >> 16));            \
    p2 += dv * bf2f((unsigned short)(hv.y & 0xFFFF));         \
    p3 += dv * bf2f((unsigned short)(hv.y >> 16));            \
    p4 += dv * bf2f((unsigned short)(hv.z & 0xFFFF));         \
    p5 += dv * bf2f((unsigned short)(hv.z >> 16));            \
    p6 += dv * bf2f((unsigned short)(hv.w & 0xFFFF));         \
    p7 += dv * bf2f((unsigned short)(hv.w >> 16));

// r7/r10-proven gather, fp32 output (UNCHANGED).
__global__ void k_gather(const int* __restrict__ adj, const int* __restrict__ cnt,
                         const int* __restrict__ deg,
                         const unsigned short* __restrict__ H,
                         float* __restrict__ out) {
    int wave = threadIdx.x >> 6;
    int lane = threadIdx.x & 63;
    int s = blockIdx.x * 4 + wave;  // N = 2500*4 exactly
    int half = lane >> 5, hl = lane & 31;
    const uint4* H16 = (const uint4*)H;
    float ds = rsqrtf((float)deg[s]);
    int c = cnt[s]; if (c > DEGCAP) c = DEGCAP;
    const int* a = adj + s * DEGCAP;
    int tl = 0; float dl = 0.0f;
    if (lane < c) { tl = a[lane]; dl = rsqrtf((float)deg[tl]); }

    uint4 hs = H16[s * 32 + hl];
    float p0, p1, p2, p3, p4, p5, p6, p7;
    {
        float w = half ? 0.0f : ds;
        p0 = w * bf2f((unsigned short)(hs.x & 0xFFFF));
        p1 = w * bf2f((unsigned short)(hs.x >> 16));
        p2 = w * bf2f((unsigned short)(hs.y & 0xFFFF));
        p3 = w * bf2f((unsigned short)(hs.y >> 16));
        p4 = w * bf2f((unsigned short)(hs.z & 0xFFFF));
        p5 = w * bf2f((unsigned short)(hs.z >> 16));
        p6 = w * bf2f((unsigned short)(hs.w & 0xFFFF));
        p7 = w * bf2f((unsigned short)(hs.w >> 16));
    }
    int cc = c < 64 ? c : 64;
    for (int i = 0; i < cc; i += 8) {
        int i0 = i + half, i1 = i + 2 + half, i2 = i + 4 + half, i3 = i + 6 + half;
        int t0 = __shfl(tl, i0), t1 = __shfl(tl, i1);
        int t2 = __shfl(tl, i2), t3 = __shfl(tl, i3);
        float d0 = __shfl(dl, i0), d1 = __shfl(dl, i1);
        float d2 = __shfl(dl, i2), d3 = __shfl(dl, i3);
        uint4 h0 = H16[t0 * 32 + hl];
        uint4 h1 = H16[t1 * 32 + hl];
        uint4 h2 = H16[t2 * 32 + hl];
        uint4 h3 = H16[t3 * 32 + hl];
        ACC8(h0, d0) ACC8(h1, d1) ACC8(h2, d2) ACC8(h3, d3)
    }
    for (int i = 64; i < c; ++i) {
        int t = a[i];
        float d = half ? 0.0f : rsqrtf((float)deg[t]);
        uint4 h = H16[t * 32 + hl];
        ACC8(h, d)
    }
    p0 += __shfl(p0, lane ^ 32); p1 += __shfl(p1, lane ^ 32);
    p2 += __shfl(p2, lane ^ 32); p3 += __shfl(p3, lane ^ 32);
    p4 += __shfl(p4, lane ^ 32); p5 += __shfl(p5, lane ^ 32);
    p6 += __shfl(p6, lane ^ 32); p7 += __shfl(p7, lane ^ 32);
    p0 = fmaxf(p0 * ds, 0.0f); p1 = fmaxf(p1 * ds, 0.0f);
    p2 = fmaxf(p2 * ds, 0.0f); p3 = fmaxf(p3 * ds, 0.0f);
    p4 = fmaxf(p4 * ds, 0.0f); p5 = fmaxf(p5 * ds, 0.0f);
    p6 = fmaxf(p6 * ds, 0.0f); p7 = fmaxf(p7 * ds, 0.0f);
    float4 o;
    if (half) { o.x = p4; o.y = p5; o.z = p6; o.w = p7; }
    else      { o.x = p0; o.y = p1; o.z = p2; o.w = p3; }
    ((float4*)out)[s * 64 + hl * 2 + half] = o;
}

extern "C" void kernel_launch(void* const* d_in, const int* in_sizes, int n_in,
                              void* d_out, int out_size, void* d_ws, size_t ws_size,
                              hipStream_t stream) {
    const float* X = (const float*)d_in[0];
    const float* W = (const float*)d_in[1];
    const int* edges = (const int*)d_in[2];

    char* ws = (char*)d_ws;
    int* deg           = (int*)(ws + OFF_DEG);
    int* cnt           = (int*)(ws + OFF_CNT);
    int* adj           = (int*)(ws + OFF_ADJ);
    unsigned short* Wt = (unsigned short*)(ws + OFF_WT);
    unsigned short* H  = (unsigned short*)(ws + OFF_H);
    int* region        = (int*)(ws + OFF_REG);
    unsigned* part32   = (unsigned*)(ws + OFF_PART);

    k_pre<<<64, 256, 0, stream>>>(W, Wt);
    k_bucket_gemm<<<BKT_BLKS + GEMM_BLKS, 256, 0, stream>>>(edges, region, X, Wt, H);
    k_fillscan<<<NG, 512, 0, stream>>>(region, adj, cnt, part32);
    k_deg<<<(N / 4 + 255) / 256, 256, 0, stream>>>(part32, deg);
    k_gather<<<N / 4, 256, 0, stream>>>(adj, cnt, deg, H, (float*)d_out);
}

// Round 12
// 126.966 us; speedup vs baseline: 1.4814x; 1.0798x over previous
//
#include <hip/hip_runtime.h>
#include <hip/hip_bf16.h>

// GCN layer: out = relu( D^-1/2 (dedup(A) + I) D^-1/2 (X @ W) )
// N=10000, E=320000, F=256.
// Storage: fp32 X/W/out (PROVEN). Edges: int32 expected, int64 tolerated
// via per-wave ballot detect.
// Cost model (r1-r11 measured):
//  - ~300k+ device-scope atomic RMWs cost 45-50us regardless of target
//    size/locality/chain structure -> ZERO global atomics anywhere.
//  - Redundant multi-block streaming = latency-bound (r9: 88us).
//  - acc[16] GEMM starved regalloc (r8); GEMM-v2 = LDS-staged X + acc[4].
//  - LDS atomics cheap; block-level fusion safe (r3), thread-level not (r6).
//  - r11 (137us, best): all kernels < 44us. Remaining waste: region was
//    bkt[400][12] per 256-edge block = 5.3% slot utilization -> 24 MB
//    written + 24 MB read (48B strided, ~2x over-fetch) for 1.28 MB payload.
// THIS ROUND: 2048-edge bucket blocks (157 x 512 thr, 4 edges/thr).
//  Poisson(5.12), cap 28 (overflow P ~ 2e-7): region 24 -> 7 MB, fillscan
//  chunk 48 -> 112 B. LDS union {buckets | GEMM stage}. GEMM blocks now
//  512 thr / 32 rows (2 strips x 4 col-groups, guarded tail).
// 5 launches: k_pre(Wt) -> k_bucket_gemm -> k_fillscan -> k_deg -> k_gather.
//
// ws layout (bytes), ~20.2 MB (ws is 256 MiB):
//   deg    i32[N]           @ 0
//   cnt    i32[N]           @ 40,960
//   adj    i32[N*96]        @ 81,920
//   Wt     bf16[F*F]        @ 3,921,920
//   H      bf16[N*F]        @ 4,052,992
//   region i32[157*11200]   @ 9,172,992   (7.03 MB bucket blobs)
//   part32 u32[400*2500]    @ 16,206,592  (4 MB byte-lane deg partials)

constexpr int N = 10000;
constexpr int E = 320000;
constexpr int F = 256;
constexpr int DEGCAP = 96;   // Poisson(32): P(any deduped degree >= 96) ~ 1e-16
constexpr int GROWS = 25;    // rows per group (fillscan block)
constexpr int NG = N / GROWS;        // 400 groups
constexpr int EPB = 2048;    // edges per bucket block
constexpr int BCAP = 28;     // Poisson(5.12): P(>28) ~ 3e-12 x 63k pairs ~ 2e-7
constexpr int REG_PB = NG * BCAP;    // 11200 ints per source block

constexpr int BKT_BLKS  = (E + EPB - 1) / EPB;  // 157 (last block 1536 edges)
constexpr int GEMM_BLKS = (N + 31) / 32;        // 313 (last block 16 rows)

constexpr size_t OFF_DEG  = 0;
constexpr size_t OFF_CNT  = 40960;
constexpr size_t OFF_ADJ  = 81920;
constexpr size_t OFF_WT   = OFF_ADJ + 4ull * N * DEGCAP;        // 3,921,920
constexpr size_t OFF_H    = OFF_WT + 2ull * F * F;              // 4,052,992
constexpr size_t OFF_REG  = OFF_H + 2ull * N * F;               // 9,172,992
constexpr size_t OFF_PART = OFF_REG + 4ull * BKT_BLKS * REG_PB; // 16,206,592

typedef short s8v __attribute__((ext_vector_type(8)));   // 8 bf16 = 4 VGPRs
typedef float f4v __attribute__((ext_vector_type(4)));   // MFMA accumulator
typedef unsigned u4v __attribute__((ext_vector_type(4)));

__device__ __forceinline__ float bf2f(unsigned short u) {
    union { unsigned u; float f; } c; c.u = (unsigned)u << 16; return c.f;
}
__device__ __forceinline__ unsigned short f2bf(float f) {
    union { __hip_bfloat16 b; unsigned short s; } c; c.b = __float2bfloat16(f); return c.s;
}

// 64 blocks: W (fp32) -> Wt (bf16, transposed). Region needs no prefill
// (raw blob flush writes every byte); cnt/deg/part written downstream.
__global__ void k_pre(const float* __restrict__ W, unsigned short* __restrict__ Wt) {
    __shared__ unsigned short ls[4][F];
    int n0 = blockIdx.x * 4;
    int k = threadIdx.x;
    float4 v = *(const float4*)&W[k * F + n0];
    ls[0][k] = f2bf(v.x); ls[1][k] = f2bf(v.y);
    ls[2][k] = f2bf(v.z); ls[3][k] = f2bf(v.w);
    __syncthreads();
    int nn = threadIdx.x >> 6;
    int kk = (threadIdx.x & 63) * 4;
    uint2 o;
    o.x = (unsigned)ls[nn][kk]     | ((unsigned)ls[nn][kk + 1] << 16);
    o.y = (unsigned)ls[nn][kk + 2] | ((unsigned)ls[nn][kk + 3] << 16);
    *(uint2*)&Wt[(n0 + nn) * F + kk] = o;
}

// Fused bucket + GEMM-v2, block-level split, 512 threads.
// Blocks [0, BKT_BLKS): 2048 edges -> 400 row-group LDS buckets (cap 28,
//   init -1), flush RAW bkt blob (44.8 KB) contiguous -> region[block].
//   Packed entry: (s % 25) << 14 | t; -1 = empty. Zero global atomics.
// Blocks [BKT_BLKS, +GEMM_BLKS): H = bf16(X) @ bf16(W), MFMA 16x16x32.
//   32 rows/block staged in LDS [32][264] (pad kills bank conflicts);
//   wave w: strip w>>2 (16 rows), col-group w&3 (4 tiles, acc[4]=16 VGPR).
//   C layout: col=lane&15, row=(lane>>4)*4+reg [learn_hip m89/m91].
__global__ void __launch_bounds__(512) k_bucket_gemm(
    const int* __restrict__ edges, int* __restrict__ region,
    const float* __restrict__ X, const unsigned short* __restrict__ Wt,
    unsigned short* __restrict__ H) {
    __shared__ union U {
        struct { int bkt[NG][BCAP]; int bcnt[NG]; } b;  // 46,400 B
        unsigned short lsA[32][264];                    // 16,896 B
    } sh;
    int tid = threadIdx.x;

    if (blockIdx.x < BKT_BLKS) {
        int probe = edges[2 * (tid & 63) + 1];
        bool is32 = __ballot(probe != 0) != 0ull;  // wave-uniform dtype detect
        for (int i = tid; i < NG; i += 512) sh.b.bcnt[i] = 0;
        int4 mone; mone.x = -1; mone.y = -1; mone.z = -1; mone.w = -1;
        int4* b4 = (int4*)&sh.b.bkt[0][0];
        for (int i = tid; i < REG_PB / 4; i += 512) b4[i] = mone;
        __syncthreads();
#pragma unroll
        for (int k = 0; k < EPB / 512; ++k) {
            int e = blockIdx.x * EPB + k * 512 + tid;
            if (e >= E) break;  // wave-uniform only in last block's tail
            int s, t;
            if (is32) { s = edges[e];     t = edges[E + e]; }
            else      { s = edges[2 * e]; t = edges[2 * E + 2 * e]; }
            if ((unsigned)s < (unsigned)N && (unsigned)t < (unsigned)N) {
                int g = s / GROWS;
                int v = ((s - g * GROWS) << 14) | t;
                int pos = atomicAdd(&sh.b.bcnt[g], 1);  // LDS atomic: cheap
                if (pos < BCAP) sh.b.bkt[g][pos] = v;
            }
        }
        __syncthreads();
        int4* dst = (int4*)(region + (size_t)blockIdx.x * REG_PB);
        for (int i = tid; i < REG_PB / 4; i += 512) dst[i] = b4[i];
        return;
    }
    // --- GEMM-v2 path: 32 rows per block ---
    int r0 = (blockIdx.x - BKT_BLKS) * 32;
    {   // stage X rows -> LDS bf16 (guard tail rows >= N)
        int row = tid >> 4, seg = tid & 15;
        if (r0 + row < N) {
            const float4* src = (const float4*)(X + (r0 + row) * F + seg * 16);
#pragma unroll
            for (int j = 0; j < 4; ++j) {
                float4 v = src[j];
                uint2 o;
                o.x = (unsigned)f2bf(v.x) | ((unsigned)f2bf(v.y) << 16);
                o.y = (unsigned)f2bf(v.z) | ((unsigned)f2bf(v.w) << 16);
                *(uint2*)&sh.lsA[row][seg * 16 + j * 4] = o;
            }
        }
    }
    __syncthreads();
    int lane = tid & 63, wv = tid >> 6;
    int sl = wv >> 2;            // strip 0/1 (rows r0+sl*16 .. +16)
    int cg = wv & 3;             // col-group (4 tiles)
    if (r0 + sl * 16 >= N) return;  // tail block: strip 1 empty
    int m = lane & 15, q = lane >> 4;
    const s8v* B = (const s8v*)(Wt + m * F + q * 8);
    f4v acc[4] = {};
#pragma unroll
    for (int kk = 0; kk < 8; ++kk) {
        s8v af = *(const s8v*)&sh.lsA[sl * 16 + m][kk * 32 + q * 8];
#pragma unroll
        for (int tt = 0; tt < 4; ++tt) {
            int t = cg * 4 + tt;
            s8v bf = B[t * 512 + kk * 4];
            acc[tt] = __builtin_amdgcn_mfma_f32_16x16x32_bf16(af, bf, acc[tt], 0, 0, 0);
        }
    }
#pragma unroll
    for (int tt = 0; tt < 4; ++tt) {
        int col = (cg * 4 + tt) * 16 + m;
#pragma unroll
        for (int i = 0; i < 4; ++i)
            H[(r0 + sl * 16 + q * 4 + i) * F + col] = f2bf(acc[tt][i]);
    }
}

// Dedup + scan, zero global atomics, every region byte read exactly once.
// Block g: read region[j][g*28 .. +28) for all j (7 uint4, 112B chunks),
// ds_or valid entries into 25x320-word LDS bitmap; popcount + wave prefix
// -> adj/cnt. deg via byte-lane LDS counters (max 25/byte < 256), flushed
// 10KB coalesced -> part32[g].
__global__ void __launch_bounds__(512) k_fillscan(
    const int* __restrict__ region,
    int* __restrict__ adj, int* __restrict__ cnt, unsigned* __restrict__ part32) {
    __shared__ unsigned bmp[GROWS][320];  // 32,000 B
    __shared__ unsigned hist32[N / 4];    // 10,000 B
    int tid = threadIdx.x;
    {
        u4v z = {0u, 0u, 0u, 0u};
        u4v* z4 = (u4v*)&bmp[0][0];
        for (int i = tid; i < GROWS * 320 / 4; i += 512) z4[i] = z;
        u4v* h4 = (u4v*)hist32;
        for (int i = tid; i < N / 16; i += 512) h4[i] = z;
    }
    __syncthreads();

    int g = blockIdx.x;
    const u4v* reg4 = (const u4v*)region;
    for (int idx = tid; idx < BKT_BLKS * (BCAP / 4); idx += 512) {
        int j = idx / (BCAP / 4), q = idx - (BCAP / 4) * j;
        u4v v4 = reg4[(size_t)j * (REG_PB / 4) + g * (BCAP / 4) + q];
#pragma unroll
        for (int jj = 0; jj < 4; ++jj) {
            int v = (int)v4[jj];
            if (v >= 0) {
                int r = v >> 14;              // 0..24
                unsigned t = (unsigned)(v & 16383);
                atomicOr(&bmp[r][t >> 5], 1u << (t & 31));  // LDS ds_or
            }
        }
    }
    __syncthreads();

    int wave = tid >> 6, lane = tid & 63;
    for (int r = wave; r < GROWS; r += 8) {
        int s = g * GROWS + r;
        const unsigned* row = bmp[r];
        unsigned w0 = row[lane];
        unsigned w1 = row[lane + 64];
        unsigned w2 = row[lane + 128];
        unsigned w3 = row[lane + 192];
        unsigned w4 = row[lane + 256];
        int pc = __popc(w0) + __popc(w1) + __popc(w2) + __popc(w3) + __popc(w4);
        int sc = pc;
#pragma unroll
        for (int d = 1; d < 64; d <<= 1) {
            int v = __shfl_up(sc, d);
            if (lane >= d) sc += v;
        }
        int o = sc - pc;
        if (lane == 63) cnt[s] = sc < DEGCAP ? sc : DEGCAP;
        int* arow = adj + s * DEGCAP;
        unsigned wvs[5] = {w0, w1, w2, w3, w4};
#pragma unroll
        for (int j = 0; j < 5; ++j) {
            unsigned w = wvs[j];
            int base = (j * 64 + lane) * 32;
            while (w) {
                int b = __ffs(w) - 1;
                w &= w - 1;
                int t = base + b;
                if (o < DEGCAP) arow[o] = t;
                ++o;
                atomicAdd(&hist32[t >> 2], 1u << ((t & 3) * 8));  // LDS byte-lane
            }
        }
    }
    __syncthreads();
    {   // coalesced 10KB partial flush
        u4v* src = (u4v*)hist32;
        u4v* dst = (u4v*)(part32 + (size_t)g * (N / 4));
        for (int i = tid; i < N / 16; i += 512) dst[i] = src[i];
    }
}

// deg[t] = 1 (self-loop) + sum of 400 byte-lane partials. Coalesced, 4 MB,
// zero atomics.
__global__ void k_deg(const unsigned* __restrict__ part32, int* __restrict__ deg) {
    int j2 = blockIdx.x * blockDim.x + threadIdx.x;  // 0..2499
    if (j2 >= N / 4) return;
    int s0 = 1, s1 = 1, s2 = 1, s3 = 1;
#pragma unroll 8
    for (int b = 0; b < NG; ++b) {
        unsigned w = part32[(size_t)b * (N / 4) + j2];
        s0 += w & 255; s1 += (w >> 8) & 255; s2 += (w >> 16) & 255; s3 += w >> 24;
    }
    int4 o; o.x = s0; o.y = s1; o.z = s2; o.w = s3;
    *(int4*)&deg[j2 * 4] = o;
}

#define ACC8(hv, dv)                                          \
    p0 += dv * bf2f((unsigned short)(hv.x & 0xFFFF));         \
    p1 += dv * bf2f((unsigned short)(hv.x >> 16));            \
    p2 += dv * bf2f((unsigned short)(hv.y & 0xFFFF));         \
    p3 += dv * bf2f((unsigned short)(hv.y >> 16));            \
    p4 += dv * bf2f((unsigned short)(hv.z & 0xFFFF));         \
    p5 += dv * bf2f((unsigned short)(hv.z >> 16));            \
    p6 += dv * bf2f((unsigned short)(hv.w & 0xFFFF));         \
    p7 += dv * bf2f((unsigned short)(hv.w >> 16));

// Proven gather, fp32 output (UNCHANGED).
__global__ void k_gather(const int* __restrict__ adj, const int* __restrict__ cnt,
                         const int* __restrict__ deg,
                         const unsigned short* __restrict__ H,
                         float* __restrict__ out) {
    int wave = threadIdx.x >> 6;
    int lane = threadIdx.x & 63;
    int s = blockIdx.x * 4 + wave;  // N = 2500*4 exactly
    int half = lane >> 5, hl = lane & 31;
    const uint4* H16 = (const uint4*)H;
    float ds = rsqrtf((float)deg[s]);
    int c = cnt[s]; if (c > DEGCAP) c = DEGCAP;
    const int* a = adj + s * DEGCAP;
    int tl = 0; float dl = 0.0f;
    if (lane < c) { tl = a[lane]; dl = rsqrtf((float)deg[tl]); }

    uint4 hs = H16[s * 32 + hl];
    float p0, p1, p2, p3, p4, p5, p6, p7;
    {
        float w = half ? 0.0f : ds;
        p0 = w * bf2f((unsigned short)(hs.x & 0xFFFF));
        p1 = w * bf2f((unsigned short)(hs.x >> 16));
        p2 = w * bf2f((unsigned short)(hs.y & 0xFFFF));
        p3 = w * bf2f((unsigned short)(hs.y >> 16));
        p4 = w * bf2f((unsigned short)(hs.z & 0xFFFF));
        p5 = w * bf2f((unsigned short)(hs.z >> 16));
        p6 = w * bf2f((unsigned short)(hs.w & 0xFFFF));
        p7 = w * bf2f((unsigned short)(hs.w >> 16));
    }
    int cc = c < 64 ? c : 64;
    for (int i = 0; i < cc; i += 8) {
        int i0 = i + half, i1 = i + 2 + half, i2 = i + 4 + half, i3 = i + 6 + half;
        int t0 = __shfl(tl, i0), t1 = __shfl(tl, i1);
        int t2 = __shfl(tl, i2), t3 = __shfl(tl, i3);
        float d0 = __shfl(dl, i0), d1 = __shfl(dl, i1);
        float d2 = __shfl(dl, i2), d3 = __shfl(dl, i3);
        uint4 h0 = H16[t0 * 32 + hl];
        uint4 h1 = H16[t1 * 32 + hl];
        uint4 h2 = H16[t2 * 32 + hl];
        uint4 h3 = H16[t3 * 32 + hl];
        ACC8(h0, d0) ACC8(h1, d1) ACC8(h2, d2) ACC8(h3, d3)
    }
    for (int i = 64; i < c; ++i) {
        int t = a[i];
        float d = half ? 0.0f : rsqrtf((float)deg[t]);
        uint4 h = H16[t * 32 + hl];
        ACC8(h, d)
    }
    p0 += __shfl(p0, lane ^ 32); p1 += __shfl(p1, lane ^ 32);
    p2 += __shfl(p2, lane ^ 32); p3 += __shfl(p3, lane ^ 32);
    p4 += __shfl(p4, lane ^ 32); p5 += __shfl(p5, lane ^ 32);
    p6 += __shfl(p6, lane ^ 32); p7 += __shfl(p7, lane ^ 32);
    p0 = fmaxf(p0 * ds, 0.0f); p1 = fmaxf(p1 * ds, 0.0f);
    p2 = fmaxf(p2 * ds, 0.0f); p3 = fmaxf(p3 * ds, 0.0f);
    p4 = fmaxf(p4 * ds, 0.0f); p5 = fmaxf(p5 * ds, 0.0f);
    p6 = fmaxf(p6 * ds, 0.0f); p7 = fmaxf(p7 * ds, 0.0f);
    float4 o;
    if (half) { o.x = p4; o.y = p5; o.z = p6; o.w = p7; }
    else      { o.x = p0; o.y = p1; o.z = p2; o.w = p3; }
    ((float4*)out)[s * 64 + hl * 2 + half] = o;
}

extern "C" void kernel_launch(void* const* d_in, const int* in_sizes, int n_in,
                              void* d_out, int out_size, void* d_ws, size_t ws_size,
                              hipStream_t stream) {
    const float* X = (const float*)d_in[0];
    const float* W = (const float*)d_in[1];
    const int* edges = (const int*)d_in[2];

    char* ws = (char*)d_ws;
    int* deg           = (int*)(ws + OFF_DEG);
    int* cnt           = (int*)(ws + OFF_CNT);
    int* adj           = (int*)(ws + OFF_ADJ);
    unsigned short* Wt = (unsigned short*)(ws + OFF_WT);
    unsigned short* H  = (unsigned short*)(ws + OFF_H);
    int* region        = (int*)(ws + OFF_REG);
    unsigned* part32   = (unsigned*)(ws + OFF_PART);

    k_pre<<<64, 256, 0, stream>>>(W, Wt);
    k_bucket_gemm<<<BKT_BLKS + GEMM_BLKS, 512, 0, stream>>>(edges, region, X, Wt, H);
    k_fillscan<<<NG, 512, 0, stream>>>(region, adj, cnt, part32);
    k_deg<<<(N / 4 + 255) / 256, 256, 0, stream>>>(part32, deg);
    k_gather<<<N / 4, 256, 0, stream>>>(adj, cnt, deg, H, (float*)d_out);
}